// Round 5
// baseline (732.445 us; speedup 1.0000x reference)
//
#include <hip/hip_runtime.h>
#include <stdint.h>

#define DEV __device__ __forceinline__

typedef unsigned short u16;
typedef __bf16 bf16x8 __attribute__((ext_vector_type(8)));
typedef float floatx4 __attribute__((ext_vector_type(4)));
typedef unsigned short u16x4 __attribute__((ext_vector_type(4)));
typedef unsigned short u16x8 __attribute__((ext_vector_type(8)));
typedef short s16x4 __attribute__((ext_vector_type(4)));

// Problem constants
// B=16, DIM=512, RES(L)=1024, NUM_HEADS=8, KEY_DIM=32, D=128, NH_KD=256, DH=1024, H_QKV=1536

DEV u16 f2bf(float x) {
  union { float f; uint32_t u; } v; v.f = x;
  uint32_t r = v.u + 0x7FFFu + ((v.u >> 16) & 1u);
  return (u16)(r >> 16);
}
DEV float bf2f(u16 x) {
  union { uint32_t u; float f; } v; v.u = ((uint32_t)x) << 16;
  return v.f;
}
DEV float loadf(const void* p, int i, int bf) {
  return bf ? bf2f(((const u16*)p)[i]) : ((const float*)p)[i];
}
DEV u16 fastbf(float x) {  // round-half-up truncation; ample tolerance
  union { float f; uint32_t u; } v; v.f = x;
  return (u16)((v.u + 0x8000u) >> 16);
}

DEV floatx4 mfma16(bf16x8 a, bf16x8 b, floatx4 c) {
  return __builtin_amdgcn_mfma_f32_16x16x32_bf16(a, b, c, 0, 0, 0);
}

// K=16 bf16 MFMA: A 2 regs (4 bf16), B 2 regs, C/D 4 regs.
#if __has_builtin(__builtin_amdgcn_mfma_f32_16x16x16bf16_1k)
DEV floatx4 mfma16k16(s16x4 a, s16x4 b, floatx4 c) {
  return __builtin_amdgcn_mfma_f32_16x16x16bf16_1k(a, b, c, 0, 0, 0);
}
#elif __has_builtin(__builtin_amdgcn_mfma_f32_16x16x16_bf16)
DEV floatx4 mfma16k16(s16x4 a, s16x4 b, floatx4 c) {
  return __builtin_amdgcn_mfma_f32_16x16x16_bf16(a, b, c, 0, 0, 0);
}
#else
DEV floatx4 mfma16k16(s16x4 a, s16x4 b, floatx4 c) {
  asm volatile("v_mfma_f32_16x16x16_bf16 %0, %1, %2, %0"
               : "+v"(c) : "v"(a), "v"(b));
  return c;
}
#endif

DEV void gl_lds16(const void* g, void* l) {
  __builtin_amdgcn_global_load_lds(
      (const __attribute__((address_space(1))) void*)g,
      (__attribute__((address_space(3))) void*)l, 16, 0, 0);
}

// ---------------------------------------------------------------- dtype sniff
__global__ void sniff(const uint32_t* __restrict__ x, int* __restrict__ flag) {
  int lane = threadIdx.x & 63;
  int hits = 0;
#pragma unroll
  for (int i = 0; i < 4; ++i) {
    uint32_t u = x[lane * 4 + i];
    int e = (u >> 7) & 0xFF;
    hits += (e >= 100 && e <= 140) ? 1 : 0;
  }
  unsigned long long m = __ballot(hits >= 3);
  if (lane == 0) *flag = (__popcll(m) >= 40) ? 1 : 0;
}

// ---------------------------------------------------------------- convert (fused)
// ranges: w_qkv 786432 | w_proj 524288 | w_dw 768 | abias 8192
__global__ __launch_bounds__(256) void cvt_all(
    const void* __restrict__ a, const void* __restrict__ b,
    const void* __restrict__ c, const void* __restrict__ d,
    u16* __restrict__ oa, u16* __restrict__ ob, u16* __restrict__ oc,
    u16* __restrict__ od, const int* __restrict__ flag) {
  int i = blockIdx.x * 256 + threadIdx.x;
  int bf = *flag;
  if (i < 786432) {
    oa[i] = bf ? ((const u16*)a)[i] : f2bf(((const float*)a)[i]);
  } else if (i < 1310720) {
    int j = i - 786432;
    ob[j] = bf ? ((const u16*)b)[j] : f2bf(((const float*)b)[j]);
  } else if (i < 1311488) {
    int j = i - 1310720;
    oc[j] = bf ? ((const u16*)c)[j] : f2bf(((const float*)c)[j]);
  } else if (i < 1319680) {
    int j = i - 1311488;
    od[j] = bf ? ((const u16*)d)[j] : f2bf(((const float*)d)[j]);
  }
}

// ---------------------------------------------------------------- params
// scl/shf layout: [0..1535] qkv, [1536..1791] dw, [1792..2303] proj
__global__ __launch_bounds__(256) void prep_params(
    const void* qg, const void* qb, const void* qm, const void* qv,
    const void* dg, const void* db, const void* dm, const void* dv,
    const void* pg, const void* pb, const void* pm, const void* pv,
    float* scl, float* shf, const int* __restrict__ flag) {
  int i = blockIdx.x * 256 + threadIdx.x;
  if (i >= 2304) return;
  int bf = *flag;
  float g, b, m, v;
  if (i < 1536)      { g = loadf(qg, i, bf); b = loadf(qb, i, bf); m = loadf(qm, i, bf); v = loadf(qv, i, bf); }
  else if (i < 1792) { int j = i - 1536; g = loadf(dg, j, bf); b = loadf(db, j, bf); m = loadf(dm, j, bf); v = loadf(dv, j, bf); }
  else               { int j = i - 1792; g = loadf(pg, j, bf); b = loadf(pb, j, bf); m = loadf(pm, j, bf); v = loadf(pv, j, bf); }
  float s = g / sqrtf(v + 1e-5f);
  scl[i] = s;
  shf[i] = b - m * s;
}

// ---------------------------------------------------------------- transpose x
// x (16,512,1024) fp32-or-bf16 -> xT (16,1024,512) bf16, 64x64 tiles
__global__ __launch_bounds__(256) void transpose_x(const void* __restrict__ x,
                                                   u16* __restrict__ xT,
                                                   const int* __restrict__ flag) {
  __shared__ __align__(16) u16 tile[64 * 72];
  const int tid = threadIdx.x;
  const int b = blockIdx.z, c0 = blockIdx.y * 64, l0 = blockIdx.x * 64;
  const int bf = *flag;
  const size_t base = ((size_t)b * 512 + c0) * 1024 + l0;
  if (bf) {
    const u16* xb = (const u16*)x + base;
#pragma unroll
    for (int it = 0; it < 4; ++it) {
      int flat = it * 256 + tid;
      int row = flat >> 4, c4 = flat & 15;
      u16x4 v = *(const u16x4*)(xb + (size_t)row * 1024 + c4 * 4);
      tile[(c4 * 4 + 0) * 72 + row] = v.x;
      tile[(c4 * 4 + 1) * 72 + row] = v.y;
      tile[(c4 * 4 + 2) * 72 + row] = v.z;
      tile[(c4 * 4 + 3) * 72 + row] = v.w;
    }
  } else {
    const float* xb = (const float*)x + base;
#pragma unroll
    for (int it = 0; it < 4; ++it) {
      int flat = it * 256 + tid;
      int row = flat >> 4, c4 = flat & 15;
      floatx4 v = *(const floatx4*)(xb + (size_t)row * 1024 + c4 * 4);
      tile[(c4 * 4 + 0) * 72 + row] = f2bf(v[0]);
      tile[(c4 * 4 + 1) * 72 + row] = f2bf(v[1]);
      tile[(c4 * 4 + 2) * 72 + row] = f2bf(v[2]);
      tile[(c4 * 4 + 3) * 72 + row] = f2bf(v[3]);
    }
  }
  __syncthreads();
  u16* xTb = xT + ((size_t)b * 1024 + l0) * 512 + c0;
#pragma unroll
  for (int it = 0; it < 4; ++it) {
    int flat = it * 256 + tid;
    int row = flat >> 4, c4 = flat & 15;
    u16x4 v = *(const u16x4*)&tile[row * 72 + c4 * 4];
    *(u16x4*)(xTb + (size_t)row * 512 + c4 * 4) = v;
  }
}

// ---------------------------------------------------------------- GEMM + BN
// Y[b,o,l] = BN(sum_c A[o,c]*BT[b,l,c]).  A (M,K) bf16, BT (16,1024,K) bf16.
// 128x128 tile, BK=32, 4 waves each 64x64, m97-style global_load_lds staging.
template <int K>
__global__ __launch_bounds__(256) void gemm_bn(
    const u16* __restrict__ A, const u16* __restrict__ BT, u16* __restrict__ Y,
    const float* __restrict__ scl, const float* __restrict__ shf, int sclOff,
    const int* __restrict__ flag, int outFlagged) {
  __shared__ __align__(16) u16 lds[4 * 64 * 72];  // 36864 B
  const int tid = threadIdx.x, lane = tid & 63, w = tid >> 6;
  const int l15 = lane & 15, quad = lane >> 4;
  const int o_blk = blockIdx.y * 128, l_blk = blockIdx.x * 128, b = blockIdx.z;
  const int o_off = (w >> 1) * 64, l_off = (w & 1) * 64;
  const u16* BTb = BT + (size_t)b * 1024 * K;

  floatx4 acc[4][4];
#pragma unroll
  for (int i = 0; i < 4; ++i)
#pragma unroll
    for (int j = 0; j < 4; ++j) acc[i][j] = (floatx4){0.f, 0.f, 0.f, 0.f};

  for (int k0 = 0; k0 < K; k0 += 32) {
    __syncthreads();
#pragma unroll
    for (int s = 0; s < 2; ++s) {
      const int chunk = (s * 4 + w) * 1024;          // wave-uniform LDS byte base
      const int byteoff = chunk + lane * 16;
      const int row = byteoff >> 6;                  // 64 B per tile row (32 bf16)
      const int col = (byteoff & 63) >> 1;
      gl_lds16(A + (size_t)(o_blk + row) * K + k0 + col, &lds[chunk >> 1]);
      gl_lds16(BTb + (size_t)(l_blk + row) * K + k0 + col, &lds[4096 + (chunk >> 1)]);
    }
    __syncthreads();
    bf16x8 af[4], bfr[4];
#pragma unroll
    for (int ir = 0; ir < 4; ++ir)
      af[ir] = *(const bf16x8*)&lds[(o_off + 16 * ir + l15) * 32 + quad * 8];
#pragma unroll
    for (int jc = 0; jc < 4; ++jc)
      bfr[jc] = *(const bf16x8*)&lds[4096 + (l_off + 16 * jc + l15) * 32 + quad * 8];
#pragma unroll
    for (int ir = 0; ir < 4; ++ir)
#pragma unroll
      for (int jc = 0; jc < 4; ++jc)
        acc[ir][jc] = mfma16(af[ir], bfr[jc], acc[ir][jc]);
  }
  __syncthreads();
  // epilogue: BN, bf16, bounce through LDS for coalesced stores
  u16* eb = &lds[w * 4608];  // 64 x 72 u16 per wave
#pragma unroll
  for (int ir = 0; ir < 4; ++ir) {
#pragma unroll
    for (int r = 0; r < 4; ++r) {
      int rloc = 16 * ir + quad * 4 + r;
      int o = o_blk + o_off + rloc;
      float s = scl[sclOff + o], hh = shf[sclOff + o];
#pragma unroll
      for (int jc = 0; jc < 4; ++jc)
        eb[rloc * 72 + 16 * jc + l15] = f2bf(acc[ir][jc][r] * s + hh);
    }
  }
  asm volatile("s_waitcnt lgkmcnt(0)" ::: "memory");
  const int M = gridDim.y * 128;
  const size_t ybase = ((size_t)b * M + o_blk + o_off) * 1024 + l_blk + l_off;
  const int outbf = outFlagged ? *flag : 1;
  if (outbf) {
#pragma unroll
    for (int it = 0; it < 8; ++it) {
      int flat = it * 64 + lane;
      int row = flat >> 3, g = flat & 7;
      u16x8 v = *(const u16x8*)&eb[row * 72 + g * 8];
      *(u16x8*)(Y + ybase + (size_t)row * 1024 + g * 8) = v;
    }
  } else {
    float* Yf = (float*)Y;
#pragma unroll
    for (int it = 0; it < 8; ++it) {
      int flat = it * 64 + lane;
      int row = flat >> 3, g = flat & 7;
      u16x8 v = *(const u16x8*)&eb[row * 72 + g * 8];
      floatx4 lo, hi;
#pragma unroll
      for (int t = 0; t < 4; ++t) { lo[t] = bf2f(v[t]); hi[t] = bf2f(v[4 + t]); }
      *(floatx4*)(Yf + ybase + (size_t)row * 1024 + g * 8) = lo;
      *(floatx4*)(Yf + ybase + (size_t)row * 1024 + g * 8 + 4) = hi;
    }
  }
}

// ---------------------------------------------------------------- dwconv q + pack q,k
__global__ __launch_bounds__(256) void dwconv_pack(
    const u16* __restrict__ qkv, const u16* __restrict__ w_dw,
    const float* __restrict__ scl, const float* __restrict__ shf,
    u16* __restrict__ qT, u16* __restrict__ kT) {
  __shared__ __align__(16) u16 lds[256 * 36];
  const int tid = threadIdx.x;
  const int lch = blockIdx.x, h = blockIdx.y, b = blockIdx.z;
  const int r = tid >> 3, seg = tid & 7;
  const int l0 = lch * 256 + seg * 32;
  {  // q: conv3 + BN, write transposed to LDS
    const int o = h * 32 + r;
    const u16* base = qkv + ((size_t)b * 1536 + o) * 1024;
    float w0 = bf2f(w_dw[o * 3 + 0]), w1 = bf2f(w_dw[o * 3 + 1]), w2 = bf2f(w_dw[o * 3 + 2]);
    float sc = scl[1536 + o], sh = shf[1536 + o];
    float prev = (l0 > 0) ? bf2f(base[l0 - 1]) : 0.f;
    float cur = bf2f(base[l0]);
#pragma unroll 4
    for (int j = 0; j < 32; ++j) {
      int lg = l0 + j;
      float nxt = (lg + 1 < 1024) ? bf2f(base[lg + 1]) : 0.f;
      lds[(seg * 32 + j) * 36 + r] = f2bf((w0 * prev + w1 * cur + w2 * nxt) * sc + sh);
      prev = cur; cur = nxt;
    }
  }
  __syncthreads();
  {
    const size_t qTb = (((size_t)b * 8 + h) * 1024 + lch * 256) * 32;
#pragma unroll
    for (int it = 0; it < 8; ++it) {
      int flat = it * 256 + tid;
      int ll = flat >> 3, g = flat & 7;
      u16x4 v = *(const u16x4*)&lds[ll * 36 + g * 4];
      *(u16x4*)(qT + qTb + (size_t)ll * 32 + g * 4) = v;
    }
  }
  __syncthreads();
  {  // k: pure transpose
    const int o = 256 + h * 32 + r;
    const u16* base = qkv + ((size_t)b * 1536 + o) * 1024;
#pragma unroll 8
    for (int j = 0; j < 32; ++j) lds[(seg * 32 + j) * 36 + r] = base[l0 + j];
  }
  __syncthreads();
  {
    const size_t kTb = (((size_t)b * 8 + h) * 1024 + lch * 256) * 32;
#pragma unroll
    for (int it = 0; it < 8; ++it) {
      int flat = it * 256 + tid;
      int ll = flat >> 3, g = flat & 7;
      u16x4 v = *(const u16x4*)&lds[ll * 36 + g * 4];
      *(u16x4*)(kT + kTb + (size_t)ll * 32 + g * 4) = v;
    }
  }
}

// ---------------------------------------------------------------- flash attention
// One block = (b,h,64 n-rows); 4 waves x 16 rows.  No-max softmax.
// Layout identity: S^T = mfma_16x16x32(K-frag, Q-frag) lands in C/D layout
// (m=quad*4+reg, n=lane&15) which IS the B-operand layout of
// v_mfma_f32_16x16x16_bf16 (k=quad*4+j, n=lane&15).  So exp+pack happens
// in-lane and P feeds PV directly from registers -- no LDS round-trip,
// no cross-lane.  V A-frag (d=lane&15, m=quad*4+j) reads V's natural
// (d,m)-contiguous layout as 8B loads.  O^T accumulates in 32 AGPRs.
__global__ __launch_bounds__(256) void attn(
    const u16* __restrict__ qT, const u16* __restrict__ kT,
    const u16* __restrict__ qkv, const u16* __restrict__ ab,
    u16* __restrict__ OT) {
  __shared__ __align__(16) float biasE[2048];
  const int tid = threadIdx.x, lane = tid & 63, w = tid >> 6;
  const int l15 = lane & 15, quad = lane >> 4;
  const int id = blockIdx.x;
  const int pair = id & 127, nb = id >> 7;     // id%8 == h -> same-XCD for (b,h)
  const int b = pair >> 3, h = pair & 7;
  for (int i = tid; i < 2048; i += 256) {
    int d = i - 1024;
    int idx = d < 0 ? -d : d;
    if (idx > 1023) idx = 1023;
    biasE[i] = bf2f(ab[h * 1024 + idx]) * 1.44269504088896340f;
  }
  __syncthreads();
  const int n0 = nb * 64 + w * 16;
  const size_t bh = ((size_t)b * 8 + h) * 1024;
  const u16* kTb = kT + bh * 32;
  const u16* vb = qkv + ((size_t)b * 1536 + 512 + h * 128) * 1024;
  const bf16x8 qf = *(const bf16x8*)(qT + bh * 32 + (size_t)(n0 + l15) * 32 + quad * 8);
  floatx4 oacc[8];
#pragma unroll
  for (int j = 0; j < 8; ++j) oacc[j] = (floatx4){0.f, 0.f, 0.f, 0.f};
  float rs = 0.f;
  const float* bp = &biasE[1024 + n0 + l15 - quad * 4];
  constexpr float c1 = 0.17677669529663689f * 1.44269504088896340f;  // scale*log2e
  const floatx4 zf = (floatx4){0.f, 0.f, 0.f, 0.f};

  for (int m0 = 0; m0 < 1024; m0 += 32) {
    bf16x8 kf0 = *(const bf16x8*)(kTb + (size_t)(m0 + l15) * 32 + quad * 8);
    bf16x8 kf1 = *(const bf16x8*)(kTb + (size_t)(m0 + 16 + l15) * 32 + quad * 8);
    // S^T tiles: row(reg)=m-within-16, col(lane&15)=n
    floatx4 s0 = mfma16(kf0, qf, zf);
    floatx4 s1 = mfma16(kf1, qf, zf);
    const float* bpm = bp - m0 - 19;  // offsets 19-r (m-tile 0), 3-r (m-tile 1)
    s16x4 pf0, pf1;
#pragma unroll
    for (int r = 0; r < 4; ++r) {
      float p0 = __builtin_amdgcn_exp2f(s0[r] * c1 + bpm[19 - r]);
      float p1 = __builtin_amdgcn_exp2f(s1[r] * c1 + bpm[3 - r]);
      rs += p0 + p1;
      pf0[r] = (short)fastbf(p0);
      pf1[r] = (short)fastbf(p1);
    }
#pragma unroll
    for (int jd = 0; jd < 8; ++jd) {
      const u16* vr = vb + (size_t)(16 * jd + l15) * 1024 + m0 + quad * 4;
      s16x4 v0 = *(const s16x4*)vr;
      s16x4 v1 = *(const s16x4*)(vr + 16);
      oacc[jd] = mfma16k16(v0, pf0, oacc[jd]);
      oacc[jd] = mfma16k16(v1, pf1, oacc[jd]);
    }
  }
  // rowsum: lanes sharing l15 across the 4 quads partition m -> 2-step reduce
  rs += __shfl_xor(rs, 16, 64);
  rs += __shfl_xor(rs, 32, 64);
  float inv = __builtin_amdgcn_rcpf(rs);
  // O^T element (d = 16*jd + quad*4 + r, n = n0 + l15); OT (b, n, h*128+d)
  u16* OTb = OT + ((size_t)b * 1024 + n0 + l15) * 1024 + h * 128 + quad * 4;
#pragma unroll
  for (int jd = 0; jd < 8; ++jd) {
    u16x4 o;
#pragma unroll
    for (int r = 0; r < 4; ++r) {
      float v = oacc[jd][r] * inv;
      v = v > 0.f ? v : 0.f;
      o[r] = fastbf(v);
    }
    *(u16x4*)(OTb + 16 * jd) = o;
  }
}

// ---------------------------------------------------------------- launch
extern "C" void kernel_launch(void* const* d_in, const int* in_sizes, int n_in,
                              void* d_out, int out_size, void* d_ws, size_t ws_size,
                              hipStream_t stream) {
  const void* x      = d_in[0];
  const void* w_qkv  = d_in[1];
  const void* qkv_g  = d_in[2];
  const void* qkv_b  = d_in[3];
  const void* qkv_m  = d_in[4];
  const void* qkv_v  = d_in[5];
  const void* w_dw   = d_in[6];
  const void* dw_g   = d_in[7];
  const void* dw_b   = d_in[8];
  const void* dw_m   = d_in[9];
  const void* dw_v   = d_in[10];
  const void* w_proj = d_in[11];
  const void* proj_g = d_in[12];
  const void* proj_b = d_in[13];
  const void* proj_m = d_in[14];
  const void* proj_v = d_in[15];
  const void* abias  = d_in[16];

  char* ws = (char*)d_ws;
  u16*   xT      = (u16*)(ws);                   // 16,777,216 B
  u16*   qkv     = (u16*)(ws + 16777216);        // 50,331,648 B
  u16*   qT      = (u16*)(ws + 67108864);        //  8,388,608 B
  u16*   kT      = (u16*)(ws + 75497472);        //  8,388,608 B
  u16*   OT      = (u16*)(ws + 83886080);        // 33,554,432 B
  float* scl     = (float*)(ws + 117440512);     //      9,216 B
  float* shf     = (float*)(ws + 117449728);     //      9,216 B
  u16*   wqkv_c  = (u16*)(ws + 117458944);       //  1,572,864 B
  u16*   wproj_c = (u16*)(ws + 119031808);       //  1,048,576 B
  u16*   wdw_c   = (u16*)(ws + 120080384);       //      2,048 B
  u16*   ab_c    = (u16*)(ws + 120082432);       //     16,384 B
  int*   flag    = (int*)(ws + 120098816);       //         64 B
  if (ws_size < (size_t)120098880) return;

  sniff<<<1, 64, 0, stream>>>((const uint32_t*)x, flag);
  cvt_all<<<5155, 256, 0, stream>>>(w_qkv, w_proj, w_dw, abias,
                                    wqkv_c, wproj_c, wdw_c, ab_c, flag);
  prep_params<<<9, 256, 0, stream>>>(qkv_g, qkv_b, qkv_m, qkv_v, dw_g, dw_b, dw_m,
                                     dw_v, proj_g, proj_b, proj_m, proj_v, scl, shf, flag);
  transpose_x<<<dim3(16, 8, 16), 256, 0, stream>>>(x, xT, flag);
  gemm_bn<512><<<dim3(8, 12, 16), 256, 0, stream>>>(wqkv_c, xT, qkv, scl, shf, 0, flag, 0);
  dwconv_pack<<<dim3(4, 8, 16), 256, 0, stream>>>(qkv, wdw_c, scl, shf, qT, kT);
  attn<<<2048, 256, 0, stream>>>(qT, kT, qkv, ab_c, OT);
  gemm_bn<1024><<<dim3(8, 4, 16), 256, 0, stream>>>(wproj_c, OT, (u16*)d_out, scl, shf, 1792, flag, 1);
}

// Round 6
// 279.847 us; speedup vs baseline: 2.6173x; 2.6173x over previous
//
#include <hip/hip_runtime.h>
#include <stdint.h>

#define DEV __device__ __forceinline__

typedef unsigned short u16;
typedef __bf16 bf16x8 __attribute__((ext_vector_type(8)));
typedef float floatx4 __attribute__((ext_vector_type(4)));
typedef unsigned short u16x4 __attribute__((ext_vector_type(4)));
typedef unsigned short u16x8 __attribute__((ext_vector_type(8)));
typedef short s16x4 __attribute__((ext_vector_type(4)));

// Problem constants
// B=16, DIM=512, RES(L)=1024, NUM_HEADS=8, KEY_DIM=32, D=128, NH_KD=256, DH=1024, H_QKV=1536

DEV u16 f2bf(float x) {
  union { float f; uint32_t u; } v; v.f = x;
  uint32_t r = v.u + 0x7FFFu + ((v.u >> 16) & 1u);
  return (u16)(r >> 16);
}
DEV float bf2f(u16 x) {
  union { uint32_t u; float f; } v; v.u = ((uint32_t)x) << 16;
  return v.f;
}
DEV float loadf(const void* p, int i, int bf) {
  return bf ? bf2f(((const u16*)p)[i]) : ((const float*)p)[i];
}
DEV u16 fastbf(float x) {  // round-half-up truncation; ample tolerance
  union { float f; uint32_t u; } v; v.f = x;
  return (u16)((v.u + 0x8000u) >> 16);
}

DEV floatx4 mfma16(bf16x8 a, bf16x8 b, floatx4 c) {
  return __builtin_amdgcn_mfma_f32_16x16x32_bf16(a, b, c, 0, 0, 0);
}

// K=16 bf16 MFMA: A 2 regs (4 bf16), B 2 regs, C/D 4 regs.
#if __has_builtin(__builtin_amdgcn_mfma_f32_16x16x16bf16_1k)
DEV floatx4 mfma16k16(s16x4 a, s16x4 b, floatx4 c) {
  return __builtin_amdgcn_mfma_f32_16x16x16bf16_1k(a, b, c, 0, 0, 0);
}
#elif __has_builtin(__builtin_amdgcn_mfma_f32_16x16x16_bf16)
DEV floatx4 mfma16k16(s16x4 a, s16x4 b, floatx4 c) {
  return __builtin_amdgcn_mfma_f32_16x16x16_bf16(a, b, c, 0, 0, 0);
}
#else
DEV floatx4 mfma16k16(s16x4 a, s16x4 b, floatx4 c) {
  asm volatile("v_mfma_f32_16x16x16_bf16 %0, %1, %2, %0"
               : "+v"(c) : "v"(a), "v"(b));
  return c;
}
#endif

DEV void gl_lds16(const void* g, void* l) {
  __builtin_amdgcn_global_load_lds(
      (const __attribute__((address_space(1))) void*)g,
      (__attribute__((address_space(3))) void*)l, 16, 0, 0);
}

// ---------------------------------------------------------------- dtype sniff
__global__ void sniff(const uint32_t* __restrict__ x, int* __restrict__ flag) {
  int lane = threadIdx.x & 63;
  int hits = 0;
#pragma unroll
  for (int i = 0; i < 4; ++i) {
    uint32_t u = x[lane * 4 + i];
    int e = (u >> 7) & 0xFF;
    hits += (e >= 100 && e <= 140) ? 1 : 0;
  }
  unsigned long long m = __ballot(hits >= 3);
  if (lane == 0) *flag = (__popcll(m) >= 40) ? 1 : 0;
}

// ---------------------------------------------------------------- convert (fused)
// ranges: w_qkv 786432 | w_proj 524288 | w_dw 768 | abias 8192
__global__ __launch_bounds__(256) void cvt_all(
    const void* __restrict__ a, const void* __restrict__ b,
    const void* __restrict__ c, const void* __restrict__ d,
    u16* __restrict__ oa, u16* __restrict__ ob, u16* __restrict__ oc,
    u16* __restrict__ od, const int* __restrict__ flag) {
  int i = blockIdx.x * 256 + threadIdx.x;
  int bf = *flag;
  if (i < 786432) {
    oa[i] = bf ? ((const u16*)a)[i] : f2bf(((const float*)a)[i]);
  } else if (i < 1310720) {
    int j = i - 786432;
    ob[j] = bf ? ((const u16*)b)[j] : f2bf(((const float*)b)[j]);
  } else if (i < 1311488) {
    int j = i - 1310720;
    oc[j] = bf ? ((const u16*)c)[j] : f2bf(((const float*)c)[j]);
  } else if (i < 1319680) {
    int j = i - 1311488;
    od[j] = bf ? ((const u16*)d)[j] : f2bf(((const float*)d)[j]);
  }
}

// ---------------------------------------------------------------- params
// scl/shf layout: [0..1535] qkv, [1536..1791] dw, [1792..2303] proj
__global__ __launch_bounds__(256) void prep_params(
    const void* qg, const void* qb, const void* qm, const void* qv,
    const void* dg, const void* db, const void* dm, const void* dv,
    const void* pg, const void* pb, const void* pm, const void* pv,
    float* scl, float* shf, const int* __restrict__ flag) {
  int i = blockIdx.x * 256 + threadIdx.x;
  if (i >= 2304) return;
  int bf = *flag;
  float g, b, m, v;
  if (i < 1536)      { g = loadf(qg, i, bf); b = loadf(qb, i, bf); m = loadf(qm, i, bf); v = loadf(qv, i, bf); }
  else if (i < 1792) { int j = i - 1536; g = loadf(dg, j, bf); b = loadf(db, j, bf); m = loadf(dm, j, bf); v = loadf(dv, j, bf); }
  else               { int j = i - 1792; g = loadf(pg, j, bf); b = loadf(pb, j, bf); m = loadf(pm, j, bf); v = loadf(pv, j, bf); }
  float s = g / sqrtf(v + 1e-5f);
  scl[i] = s;
  shf[i] = b - m * s;
}

// ---------------------------------------------------------------- transpose x
// x (16,512,1024) fp32-or-bf16 -> xT (16,1024,512) bf16, 64x64 tiles
__global__ __launch_bounds__(256) void transpose_x(const void* __restrict__ x,
                                                   u16* __restrict__ xT,
                                                   const int* __restrict__ flag) {
  __shared__ __align__(16) u16 tile[64 * 72];
  const int tid = threadIdx.x;
  const int b = blockIdx.z, c0 = blockIdx.y * 64, l0 = blockIdx.x * 64;
  const int bf = *flag;
  const size_t base = ((size_t)b * 512 + c0) * 1024 + l0;
  if (bf) {
    const u16* xb = (const u16*)x + base;
#pragma unroll
    for (int it = 0; it < 4; ++it) {
      int flat = it * 256 + tid;
      int row = flat >> 4, c4 = flat & 15;
      u16x4 v = *(const u16x4*)(xb + (size_t)row * 1024 + c4 * 4);
      tile[(c4 * 4 + 0) * 72 + row] = v.x;
      tile[(c4 * 4 + 1) * 72 + row] = v.y;
      tile[(c4 * 4 + 2) * 72 + row] = v.z;
      tile[(c4 * 4 + 3) * 72 + row] = v.w;
    }
  } else {
    const float* xb = (const float*)x + base;
#pragma unroll
    for (int it = 0; it < 4; ++it) {
      int flat = it * 256 + tid;
      int row = flat >> 4, c4 = flat & 15;
      floatx4 v = *(const floatx4*)(xb + (size_t)row * 1024 + c4 * 4);
      tile[(c4 * 4 + 0) * 72 + row] = f2bf(v[0]);
      tile[(c4 * 4 + 1) * 72 + row] = f2bf(v[1]);
      tile[(c4 * 4 + 2) * 72 + row] = f2bf(v[2]);
      tile[(c4 * 4 + 3) * 72 + row] = f2bf(v[3]);
    }
  }
  __syncthreads();
  u16* xTb = xT + ((size_t)b * 1024 + l0) * 512 + c0;
#pragma unroll
  for (int it = 0; it < 4; ++it) {
    int flat = it * 256 + tid;
    int row = flat >> 4, c4 = flat & 15;
    u16x4 v = *(const u16x4*)&tile[row * 72 + c4 * 4];
    *(u16x4*)(xTb + (size_t)row * 512 + c4 * 4) = v;
  }
}

// ---------------------------------------------------------------- GEMM + BN
// Y[b,o,l] = BN(sum_c A[o,c]*BT[b,l,c]).  A (M,K) bf16, BT (16,1024,K) bf16.
// 128x128 tile, BK=32, 4 waves each 64x64, m97-style global_load_lds staging.
template <int K>
__global__ __launch_bounds__(256) void gemm_bn(
    const u16* __restrict__ A, const u16* __restrict__ BT, u16* __restrict__ Y,
    const float* __restrict__ scl, const float* __restrict__ shf, int sclOff,
    const int* __restrict__ flag, int outFlagged) {
  __shared__ __align__(16) u16 lds[4 * 64 * 72];  // 36864 B
  const int tid = threadIdx.x, lane = tid & 63, w = tid >> 6;
  const int l15 = lane & 15, quad = lane >> 4;
  const int o_blk = blockIdx.y * 128, l_blk = blockIdx.x * 128, b = blockIdx.z;
  const int o_off = (w >> 1) * 64, l_off = (w & 1) * 64;
  const u16* BTb = BT + (size_t)b * 1024 * K;

  floatx4 acc[4][4];
#pragma unroll
  for (int i = 0; i < 4; ++i)
#pragma unroll
    for (int j = 0; j < 4; ++j) acc[i][j] = (floatx4){0.f, 0.f, 0.f, 0.f};

  for (int k0 = 0; k0 < K; k0 += 32) {
    __syncthreads();
#pragma unroll
    for (int s = 0; s < 2; ++s) {
      const int chunk = (s * 4 + w) * 1024;          // wave-uniform LDS byte base
      const int byteoff = chunk + lane * 16;
      const int row = byteoff >> 6;                  // 64 B per tile row (32 bf16)
      const int col = (byteoff & 63) >> 1;
      gl_lds16(A + (size_t)(o_blk + row) * K + k0 + col, &lds[chunk >> 1]);
      gl_lds16(BTb + (size_t)(l_blk + row) * K + k0 + col, &lds[4096 + (chunk >> 1)]);
    }
    __syncthreads();
    bf16x8 af[4], bfr[4];
#pragma unroll
    for (int ir = 0; ir < 4; ++ir)
      af[ir] = *(const bf16x8*)&lds[(o_off + 16 * ir + l15) * 32 + quad * 8];
#pragma unroll
    for (int jc = 0; jc < 4; ++jc)
      bfr[jc] = *(const bf16x8*)&lds[4096 + (l_off + 16 * jc + l15) * 32 + quad * 8];
#pragma unroll
    for (int ir = 0; ir < 4; ++ir)
#pragma unroll
      for (int jc = 0; jc < 4; ++jc)
        acc[ir][jc] = mfma16(af[ir], bfr[jc], acc[ir][jc]);
  }
  __syncthreads();
  // epilogue: BN, bf16, bounce through LDS for coalesced stores
  u16* eb = &lds[w * 4608];  // 64 x 72 u16 per wave
#pragma unroll
  for (int ir = 0; ir < 4; ++ir) {
#pragma unroll
    for (int r = 0; r < 4; ++r) {
      int rloc = 16 * ir + quad * 4 + r;
      int o = o_blk + o_off + rloc;
      float s = scl[sclOff + o], hh = shf[sclOff + o];
#pragma unroll
      for (int jc = 0; jc < 4; ++jc)
        eb[rloc * 72 + 16 * jc + l15] = f2bf(acc[ir][jc][r] * s + hh);
    }
  }
  asm volatile("s_waitcnt lgkmcnt(0)" ::: "memory");
  const int M = gridDim.y * 128;
  const size_t ybase = ((size_t)b * M + o_blk + o_off) * 1024 + l_blk + l_off;
  const int outbf = outFlagged ? *flag : 1;
  if (outbf) {
#pragma unroll
    for (int it = 0; it < 8; ++it) {
      int flat = it * 64 + lane;
      int row = flat >> 3, g = flat & 7;
      u16x8 v = *(const u16x8*)&eb[row * 72 + g * 8];
      *(u16x8*)(Y + ybase + (size_t)row * 1024 + g * 8) = v;
    }
  } else {
    float* Yf = (float*)Y;
#pragma unroll
    for (int it = 0; it < 8; ++it) {
      int flat = it * 64 + lane;
      int row = flat >> 3, g = flat & 7;
      u16x8 v = *(const u16x8*)&eb[row * 72 + g * 8];
      floatx4 lo, hi;
#pragma unroll
      for (int t = 0; t < 4; ++t) { lo[t] = bf2f(v[t]); hi[t] = bf2f(v[4 + t]); }
      *(floatx4*)(Yf + ybase + (size_t)row * 1024 + g * 8) = lo;
      *(floatx4*)(Yf + ybase + (size_t)row * 1024 + g * 8 + 4) = hi;
    }
  }
}

// ---------------------------------------------------------------- dwconv q + pack q,k
__global__ __launch_bounds__(256) void dwconv_pack(
    const u16* __restrict__ qkv, const u16* __restrict__ w_dw,
    const float* __restrict__ scl, const float* __restrict__ shf,
    u16* __restrict__ qT, u16* __restrict__ kT) {
  __shared__ __align__(16) u16 lds[256 * 36];
  const int tid = threadIdx.x;
  const int lch = blockIdx.x, h = blockIdx.y, b = blockIdx.z;
  const int r = tid >> 3, seg = tid & 7;
  const int l0 = lch * 256 + seg * 32;
  {  // q: conv3 + BN, write transposed to LDS
    const int o = h * 32 + r;
    const u16* base = qkv + ((size_t)b * 1536 + o) * 1024;
    float w0 = bf2f(w_dw[o * 3 + 0]), w1 = bf2f(w_dw[o * 3 + 1]), w2 = bf2f(w_dw[o * 3 + 2]);
    float sc = scl[1536 + o], sh = shf[1536 + o];
    float prev = (l0 > 0) ? bf2f(base[l0 - 1]) : 0.f;
    float cur = bf2f(base[l0]);
#pragma unroll 4
    for (int j = 0; j < 32; ++j) {
      int lg = l0 + j;
      float nxt = (lg + 1 < 1024) ? bf2f(base[lg + 1]) : 0.f;
      lds[(seg * 32 + j) * 36 + r] = f2bf((w0 * prev + w1 * cur + w2 * nxt) * sc + sh);
      prev = cur; cur = nxt;
    }
  }
  __syncthreads();
  {
    const size_t qTb = (((size_t)b * 8 + h) * 1024 + lch * 256) * 32;
#pragma unroll
    for (int it = 0; it < 8; ++it) {
      int flat = it * 256 + tid;
      int ll = flat >> 3, g = flat & 7;
      u16x4 v = *(const u16x4*)&lds[ll * 36 + g * 4];
      *(u16x4*)(qT + qTb + (size_t)ll * 32 + g * 4) = v;
    }
  }
  __syncthreads();
  {  // k: pure transpose
    const int o = 256 + h * 32 + r;
    const u16* base = qkv + ((size_t)b * 1536 + o) * 1024;
#pragma unroll 8
    for (int j = 0; j < 32; ++j) lds[(seg * 32 + j) * 36 + r] = base[l0 + j];
  }
  __syncthreads();
  {
    const size_t kTb = (((size_t)b * 8 + h) * 1024 + lch * 256) * 32;
#pragma unroll
    for (int it = 0; it < 8; ++it) {
      int flat = it * 256 + tid;
      int ll = flat >> 3, g = flat & 7;
      u16x4 v = *(const u16x4*)&lds[ll * 36 + g * 4];
      *(u16x4*)(kT + kTb + (size_t)ll * 32 + g * 4) = v;
    }
  }
}

// ---------------------------------------------------------------- flash attention
// Block = (b,h,128 n-rows); 4 waves x 32 rows.  No-max softmax.
// P stays in registers (S^T C/D layout == K=16 B-operand layout).
// V staged in LDS once per block per 32-m chunk (fragment-major layout:
// one aligned ds_read_b128 per lane per jd yields both m-half A-frags),
// double-buffered, one barrier/iter.  Kills the per-wave V line-traffic
// that bound R2-R5 (per-CU 4 MB -> 1 MB per pass).
__global__ __launch_bounds__(256) void attn(
    const u16* __restrict__ qT, const u16* __restrict__ kT,
    const u16* __restrict__ qkv, const u16* __restrict__ ab,
    u16* __restrict__ OT) {
  __shared__ __align__(16) float biasE[2048];
  __shared__ __align__(16) u16 ldsV[2 * 4096];  // 2 bufs x 128d x 32m
  const int tid = threadIdx.x, lane = tid & 63, w = tid >> 6;
  const int l15 = lane & 15, quad = lane >> 4;
  const int id = blockIdx.x;
  const int pair = id & 127, nb = id >> 7;     // id%8 == h -> same-XCD for (b,h)
  const int b = pair >> 3, h = pair & 7;
  for (int i = tid; i < 2048; i += 256) {
    int d = i - 1024;
    int idx = d < 0 ? -d : d;
    if (idx > 1023) idx = 1023;
    biasE[i] = bf2f(ab[h * 1024 + idx]) * 1.44269504088896340f;
  }
  const int n0 = nb * 128 + w * 32;
  const size_t bh = ((size_t)b * 8 + h) * 1024;
  const u16* kTb = kT + bh * 32;
  const u16* vb = qkv + ((size_t)b * 1536 + 512 + h * 128) * 1024;
  const bf16x8 qf0 = *(const bf16x8*)(qT + bh * 32 + (size_t)(n0 + l15) * 32 + quad * 8);
  const bf16x8 qf1 = *(const bf16x8*)(qT + bh * 32 + (size_t)(n0 + 16 + l15) * 32 + quad * 8);
  // V staging: lane covers (d0 = w*32 + lane/4 [+16], m-chunk sc = lane%3..)
  const int srow = lane >> 2, sc = lane & 3;
  const int d0 = w * 32 + srow, d1 = d0 + 16;
  const u16* sg0 = vb + (size_t)d0 * 1024 + sc * 8;
  const u16* sg1 = vb + (size_t)d1 * 1024 + sc * 8;
  // LDS slot (u16 idx): (( (d>>4)*4 + q )*16 + (d&15))*8 + mh*4 ; q = 2*(sc&1)(+1)
  const int wb0 = (((d0 >> 4) * 4 + 2 * (sc & 1)) * 16 + (d0 & 15)) * 8 + (sc >> 1) * 4;
  const int wb1 = (((d1 >> 4) * 4 + 2 * (sc & 1)) * 16 + (d1 & 15)) * 8 + (sc >> 1) * 4;

  floatx4 oacc[2][8];
#pragma unroll
  for (int i = 0; i < 2; ++i)
#pragma unroll
    for (int j = 0; j < 8; ++j) oacc[i][j] = (floatx4){0.f, 0.f, 0.f, 0.f};
  float rs0 = 0.f, rs1 = 0.f;
  constexpr float c1 = 0.17677669529663689f * 1.44269504088896340f;  // scale*log2e
  const floatx4 zf = (floatx4){0.f, 0.f, 0.f, 0.f};

  {  // prologue: stage chunk m0=0 into buffer 0
    u16x8 a0 = *(const u16x8*)sg0;
    u16x8 a1 = *(const u16x8*)sg1;
    *(u16x4*)&ldsV[wb0]       = (u16x4){a0[0], a0[1], a0[2], a0[3]};
    *(u16x4*)&ldsV[wb0 + 128] = (u16x4){a0[4], a0[5], a0[6], a0[7]};
    *(u16x4*)&ldsV[wb1]       = (u16x4){a1[0], a1[1], a1[2], a1[3]};
    *(u16x4*)&ldsV[wb1 + 128] = (u16x4){a1[4], a1[5], a1[6], a1[7]};
  }
  __syncthreads();

  for (int m0 = 0; m0 < 1024; m0 += 32) {
    const int par = (m0 >> 5) & 1;
    const bool more = (m0 + 32) < 1024;
    u16x8 a0, a1;
    if (more) {  // issue staging loads early; consumed at loop bottom
      a0 = *(const u16x8*)(sg0 + m0 + 32);
      a1 = *(const u16x8*)(sg1 + m0 + 32);
    }
    bf16x8 kf0 = *(const bf16x8*)(kTb + (size_t)(m0 + l15) * 32 + quad * 8);
    bf16x8 kf1 = *(const bf16x8*)(kTb + (size_t)(m0 + 16 + l15) * 32 + quad * 8);
    // S^T tiles s[mh][nh]: row(reg)=m-within-16 (quad*4+r), col=lane&15 (n)
    floatx4 s00 = mfma16(kf0, qf0, zf);
    floatx4 s10 = mfma16(kf1, qf0, zf);
    floatx4 s01 = mfma16(kf0, qf1, zf);
    floatx4 s11 = mfma16(kf1, qf1, zf);
    const int Cb = 1024 + n0 + l15 - quad * 4 - m0;
    float bm[4], b0v[4], bpv[4];
#pragma unroll
    for (int r = 0; r < 4; ++r) {
      bm[r]  = biasE[Cb - 16 - r];
      b0v[r] = biasE[Cb - r];
      bpv[r] = biasE[Cb + 16 - r];
    }
    s16x4 pf00, pf01, pf10, pf11;  // pf[nh][mh]
#pragma unroll
    for (int r = 0; r < 4; ++r) {
      float p00 = __builtin_amdgcn_exp2f(s00[r] * c1 + b0v[r]);
      float p01 = __builtin_amdgcn_exp2f(s10[r] * c1 + bm[r]);
      float p10 = __builtin_amdgcn_exp2f(s01[r] * c1 + bpv[r]);
      float p11 = __builtin_amdgcn_exp2f(s11[r] * c1 + b0v[r]);
      rs0 += p00 + p01;
      rs1 += p10 + p11;
      pf00[r] = (short)fastbf(p00);
      pf01[r] = (short)fastbf(p01);
      pf10[r] = (short)fastbf(p10);
      pf11[r] = (short)fastbf(p11);
    }
    const int rbase = par * 4096 + quad * 128 + l15 * 8;
#pragma unroll
    for (int jd = 0; jd < 8; ++jd) {
      u16x8 vv = *(const u16x8*)&ldsV[rbase + jd * 512];  // ds_read_b128
      s16x4 v0 = {(short)vv[0], (short)vv[1], (short)vv[2], (short)vv[3]};
      s16x4 v1 = {(short)vv[4], (short)vv[5], (short)vv[6], (short)vv[7]};
      oacc[0][jd] = mfma16k16(v0, pf00, oacc[0][jd]);
      oacc[0][jd] = mfma16k16(v1, pf01, oacc[0][jd]);
      oacc[1][jd] = mfma16k16(v0, pf10, oacc[1][jd]);
      oacc[1][jd] = mfma16k16(v1, pf11, oacc[1][jd]);
    }
    if (more) {
      u16* dst = ldsV + (par ^ 1) * 4096;
      *(u16x4*)&dst[wb0]       = (u16x4){a0[0], a0[1], a0[2], a0[3]};
      *(u16x4*)&dst[wb0 + 128] = (u16x4){a0[4], a0[5], a0[6], a0[7]};
      *(u16x4*)&dst[wb1]       = (u16x4){a1[0], a1[1], a1[2], a1[3]};
      *(u16x4*)&dst[wb1 + 128] = (u16x4){a1[4], a1[5], a1[6], a1[7]};
    }
    __syncthreads();
  }
  // rowsum: quads partition m -> reduce across quads (lanes sharing l15)
  rs0 += __shfl_xor(rs0, 16, 64);
  rs0 += __shfl_xor(rs0, 32, 64);
  rs1 += __shfl_xor(rs1, 16, 64);
  rs1 += __shfl_xor(rs1, 32, 64);
  const float inv0 = __builtin_amdgcn_rcpf(rs0);
  const float inv1 = __builtin_amdgcn_rcpf(rs1);
  // O^T elem (d = 16jd + quad*4 + r, n = n0 + 16nh + l15); OT (b, n, h*128+d)
  u16* OTb = OT + ((size_t)b * 1024 + n0 + l15) * 1024 + h * 128 + quad * 4;
#pragma unroll
  for (int jd = 0; jd < 8; ++jd) {
    u16x4 o0, o1;
#pragma unroll
    for (int r = 0; r < 4; ++r) {
      float v0 = oacc[0][jd][r] * inv0;
      float v1 = oacc[1][jd][r] * inv1;
      o0[r] = fastbf(v0 > 0.f ? v0 : 0.f);
      o1[r] = fastbf(v1 > 0.f ? v1 : 0.f);
    }
    *(u16x4*)(OTb + 16 * jd) = o0;
    *(u16x4*)(OTb + 16 * 1024 + 16 * jd) = o1;
  }
}

// ---------------------------------------------------------------- launch
extern "C" void kernel_launch(void* const* d_in, const int* in_sizes, int n_in,
                              void* d_out, int out_size, void* d_ws, size_t ws_size,
                              hipStream_t stream) {
  const void* x      = d_in[0];
  const void* w_qkv  = d_in[1];
  const void* qkv_g  = d_in[2];
  const void* qkv_b  = d_in[3];
  const void* qkv_m  = d_in[4];
  const void* qkv_v  = d_in[5];
  const void* w_dw   = d_in[6];
  const void* dw_g   = d_in[7];
  const void* dw_b   = d_in[8];
  const void* dw_m   = d_in[9];
  const void* dw_v   = d_in[10];
  const void* w_proj = d_in[11];
  const void* proj_g = d_in[12];
  const void* proj_b = d_in[13];
  const void* proj_m = d_in[14];
  const void* proj_v = d_in[15];
  const void* abias  = d_in[16];

  char* ws = (char*)d_ws;
  u16*   xT      = (u16*)(ws);                   // 16,777,216 B
  u16*   qkv     = (u16*)(ws + 16777216);        // 50,331,648 B
  u16*   qT      = (u16*)(ws + 67108864);        //  8,388,608 B
  u16*   kT      = (u16*)(ws + 75497472);        //  8,388,608 B
  u16*   OT      = (u16*)(ws + 83886080);        // 33,554,432 B
  float* scl     = (float*)(ws + 117440512);     //      9,216 B
  float* shf     = (float*)(ws + 117449728);     //      9,216 B
  u16*   wqkv_c  = (u16*)(ws + 117458944);       //  1,572,864 B
  u16*   wproj_c = (u16*)(ws + 119031808);       //  1,048,576 B
  u16*   wdw_c   = (u16*)(ws + 120080384);       //      2,048 B
  u16*   ab_c    = (u16*)(ws + 120082432);       //     16,384 B
  int*   flag    = (int*)(ws + 120098816);       //         64 B
  if (ws_size < (size_t)120098880) return;

  sniff<<<1, 64, 0, stream>>>((const uint32_t*)x, flag);
  cvt_all<<<5155, 256, 0, stream>>>(w_qkv, w_proj, w_dw, abias,
                                    wqkv_c, wproj_c, wdw_c, ab_c, flag);
  prep_params<<<9, 256, 0, stream>>>(qkv_g, qkv_b, qkv_m, qkv_v, dw_g, dw_b, dw_m,
                                     dw_v, proj_g, proj_b, proj_m, proj_v, scl, shf, flag);
  transpose_x<<<dim3(16, 8, 16), 256, 0, stream>>>(x, xT, flag);
  gemm_bn<512><<<dim3(8, 12, 16), 256, 0, stream>>>(wqkv_c, xT, qkv, scl, shf, 0, flag, 0);
  dwconv_pack<<<dim3(4, 8, 16), 256, 0, stream>>>(qkv, wdw_c, scl, shf, qT, kT);
  attn<<<1024, 256, 0, stream>>>(qT, kT, qkv, ab_c, OT);
  gemm_bn<1024><<<dim3(8, 4, 16), 256, 0, stream>>>(wproj_c, OT, (u16*)d_out, scl, shf, 1792, flag, 1);
}